// Round 3
// baseline (270.318 us; speedup 1.0000x reference)
//
#include <hip/hip_runtime.h>
#include <hip/hip_bf16.h>

// Problem constants (match reference setup_inputs)
#define BATCH 4096
#define P     64
#define L     1024            // floats per (b,p) block = 4 KiB
#define LT    256             // samples per block
#define NPAIRS (BATCH * P)    // 262144
#define WPB   4               // waves per block (256 threads)

// Wave-independent gather: each 64-lane wave owns a private 4 KiB LDS tile
// and processes one (b,p) pair per iteration with ZERO __syncthreads:
//   - lane t's 4 output indices w[4t..4t+3] are loaded once into registers
//   - prefetch next tile (4x float4/lane = 4 KiB/wave) into registers while
//     gathering the current tile (DS ops are in-order per wave, so the next
//     ds_write cannot pass this iteration's ds_read gathers)
//   - gather 4 floats/lane from own tile, store as one coalesced float4
// 32 waves/CU x 4 KiB in flight = 128 KiB/CU of MLP, far above the ~10 KB
// latency-bandwidth product -> HBM-saturating without any barrier coupling.
__global__ __launch_bounds__(256, 2)
void HardSamplingLayer_5360119186055_kernel(const float* __restrict__ x,
                                            const int* __restrict__ w,
                                            float* __restrict__ out) {
    __shared__ float tile[WPB][L];        // 16 KiB total, 4 KiB per wave

    const int t  = threadIdx.x & 63;      // lane
    const int wv = threadIdx.x >> 6;      // wave id within block
    float* mytile = tile[wv];

    // per-lane gather indices, constant across all pairs (coalesced dwordx4)
    const int4 wi = ((const int4*)w)[t];

    const int stride = gridDim.x * WPB;   // total waves in grid
    int pair = blockIdx.x * WPB + wv;
    if (pair >= NPAIRS) return;

    // prefetch first tile into registers
    {
        const float4* xp = (const float4*)(x + (size_t)pair * L);
        // fallthrough into loop with v0..v3 live
    }
    const float4* xp0 = (const float4*)(x + (size_t)pair * L);
    float4 v0 = xp0[t];
    float4 v1 = xp0[t + 64];
    float4 v2 = xp0[t + 128];
    float4 v3 = xp0[t + 192];

    while (pair < NPAIRS) {
        const int next = pair + stride;

        // commit prefetched tile to own LDS region (conflict-free b128)
        ((float4*)mytile)[t]       = v0;
        ((float4*)mytile)[t + 64]  = v1;
        ((float4*)mytile)[t + 128] = v2;
        ((float4*)mytile)[t + 192] = v3;
        __builtin_amdgcn_wave_barrier();  // pin schedule: writes before gathers

        // issue next tile's loads; their vmcnt lands at next iter's ds_write
        if (next < NPAIRS) {
            const float4* xn = (const float4*)(x + (size_t)next * L);
            v0 = xn[t];
            v1 = xn[t + 64];
            v2 = xn[t + 128];
            v3 = xn[t + 192];
        }

        // gather 4 elements from own tile (random ds_read_b32)
        float4 o;
        o.x = mytile[wi.x];
        o.y = mytile[wi.y];
        o.z = mytile[wi.z];
        o.w = mytile[wi.w];
        __builtin_amdgcn_wave_barrier();  // gathers stay before next ds_write

        // coalesced 16B/lane store: wave covers the full 1 KiB output row
        ((float4*)(out + (size_t)pair * LT))[t] = o;

        pair = next;
    }
}

extern "C" void kernel_launch(void* const* d_in, const int* in_sizes, int n_in,
                              void* d_out, int out_size, void* d_ws, size_t ws_size,
                              hipStream_t stream) {
    const float* x = (const float*)d_in[0];
    const int*   w = (const int*)d_in[1];   // integer input -> const int*
    float*     out = (float*)d_out;

    // 4096 blocks x 4 waves = 16384 waves; 262144/16384 = 16 pairs per wave,
    // exact division -> uniform trip count, tail branch false for all waves
    // simultaneously on the last iteration.
    dim3 grid(4096), block(256);
    hipLaunchKernelGGL(HardSamplingLayer_5360119186055_kernel,
                       grid, block, 0, stream, x, w, out);
}

// Round 5
// 258.060 us; speedup vs baseline: 1.0475x; 1.0475x over previous
//
#include <hip/hip_runtime.h>
#include <hip/hip_bf16.h>

// Problem constants (match reference setup_inputs)
#define BATCH 4096
#define P     64
#define L     1024            // floats per (b,p) block = 4 KiB
#define LT    256             // samples per block
#define NPAIRS (BATCH * P)    // 262144
#define WPB   4               // waves per block (256 threads)
#define NBLK  4096
#define PPW   (NPAIRS / (NBLK * WPB))   // 16 pairs per wave, contiguous

// Each 64-lane wave owns a private double-buffered 2x4 KiB LDS tile and
// processes 16 CONTIGUOUS (b,p) pairs. Staging uses global_load_lds
// (DMA direct to LDS, no VGPR round-trip, no ds_write) with hand-counted
// s_waitcnt vmcnt(4): the 4 next-tile loads stay in flight across the
// current tile's gather+store. Zero __syncthreads, zero block coupling.
//
// vmcnt ledger (FIFO): at iter i's wait point, outstanding =
//   [store(i-1)] [4 loads -> buf^1 (tile i+1)]
// vmcnt(4) drains store(i-1) and everything older, incl. tile i's loads.
// Last iter: vmcnt(0). Gather ds_reads complete (lgkmcnt) before the store
// issues, and the store issues before the next loads, so the DMA write to a
// buffer can never pass that buffer's still-pending gathers.

typedef const __attribute__((address_space(1))) void* gptr_t;
typedef __attribute__((address_space(3))) void* lptr_t;
typedef float nfloat4 __attribute__((ext_vector_type(4)));  // clang-native vec

__device__ __forceinline__ void stage_tile(const float* gsrc_lane,
                                           float* lds_base) {
    // 4 chunks x (64 lanes x 16 B) = 4 KiB; LDS dest = uniform base + lane*16
    __builtin_amdgcn_global_load_lds((gptr_t)(gsrc_lane),        (lptr_t)(lds_base),        16, 0, 0);
    __builtin_amdgcn_global_load_lds((gptr_t)(gsrc_lane + 256),  (lptr_t)(lds_base + 256),  16, 0, 0);
    __builtin_amdgcn_global_load_lds((gptr_t)(gsrc_lane + 512),  (lptr_t)(lds_base + 512),  16, 0, 0);
    __builtin_amdgcn_global_load_lds((gptr_t)(gsrc_lane + 768),  (lptr_t)(lds_base + 768),  16, 0, 0);
}

__global__ __launch_bounds__(256)
void HardSamplingLayer_5360119186055_kernel(const float* __restrict__ x,
                                            const int* __restrict__ w,
                                            float* __restrict__ out) {
    __shared__ float tile[WPB][2][L];     // 32 KiB: per-wave double buffer

    const int t  = threadIdx.x & 63;      // lane
    const int wv = threadIdx.x >> 6;      // wave id within block

    // per-lane gather indices (columns 4t..4t+3), constant across pairs
    const int4 wi = ((const int4*)w)[t];

    const int    wid   = blockIdx.x * WPB + wv;       // 0..16383
    const size_t pair0 = (size_t)wid * PPW;           // 16 contiguous pairs
    const float* gsrc  = x + pair0 * L + t * 4;       // lane's 16B slot
    float*       gdst  = out + pair0 * LT;

    // prologue: stage pair0 -> buf0
    stage_tile(gsrc, &tile[wv][0][0]);

#pragma unroll
    for (int i = 0; i < PPW; ++i) {
        const int buf = i & 1;
        if (i + 1 < PPW) {
            stage_tile(gsrc + (size_t)(i + 1) * L, &tile[wv][buf ^ 1][0]);
            asm volatile("s_waitcnt vmcnt(4)" ::: "memory");  // cur tile ready
        } else {
            asm volatile("s_waitcnt vmcnt(0)" ::: "memory");  // drain all
        }

        const float* mytile = &tile[wv][buf][0];
        nfloat4 o;
        o.x = mytile[wi.x];
        o.y = mytile[wi.y];
        o.z = mytile[wi.z];
        o.w = mytile[wi.w];

        // coalesced 16B/lane nontemporal store (full 1 KiB row per wave)
        __builtin_nontemporal_store(o, (nfloat4*)(gdst + (size_t)i * LT) + t);
    }
}

extern "C" void kernel_launch(void* const* d_in, const int* in_sizes, int n_in,
                              void* d_out, int out_size, void* d_ws, size_t ws_size,
                              hipStream_t stream) {
    const float* x = (const float*)d_in[0];
    const int*   w = (const int*)d_in[1];   // integer input -> const int*
    float*     out = (float*)d_out;

    // 4096 blocks x 4 waves x 16 pairs = 262144, exact
    dim3 grid(NBLK), block(256);
    hipLaunchKernelGGL(HardSamplingLayer_5360119186055_kernel,
                       grid, block, 0, stream, x, w, out);
}